// Round 5
// baseline (38.319 us; speedup 1.0000x reference)
//
#include <hip/hip_runtime.h>
#include <math.h>

// Problem constants
#define N_  32
#define C_  256
#define K_  6
#define M_  22
#define HO_ 17
#define P_  484            // 22*22
#define ZP_ 36             // 6*6

static constexpr int OUT0_SZ = N_ * HO_ * HO_;        // 9248
static constexpr int XF_OFF  = OUT0_SZ;
static constexpr int XF_SZ   = N_ * C_ * P_;          // 3964928
static constexpr int ZF_OFF  = XF_OFF + XF_SZ;        // 3974176

static constexpr int CORR_BLOCKS = N_ * HO_;          // 544
static constexpr int CONV_BLOCKS = N_ * 16;           // 512 (16 channels/block)
static constexpr size_t CNT_OFF_BYTES = 8192;         // counter in ws, past partials

// fast sqrt: raw v_sqrt_f32 (~1 ulp), fine vs the 6.9e-2 threshold
__device__ __forceinline__ float fsqrt(float x) { return __builtin_amdgcn_sqrtf(x); }

// DPP wave64 sum-reduction step: x += dpp_perm(x), invalid lanes contribute 0
#define DPP_ADD(x, ctrl)                                                      \
    (x) += __builtin_bit_cast(float, __builtin_amdgcn_update_dpp(             \
               0, __builtin_bit_cast(int, (x)), (ctrl), 0xF, 0xF, true))

// ---------------------------------------------------------------------------
// Single fat kernel.
// blocks [0, 544):     correlation rows + (last finisher) fused BatchNorm.
// blocks [544, 1056):  streaming conv: block=(n, 16-channel group); x float4s
//                      held in registers across an 8-iteration channel loop.
// ---------------------------------------------------------------------------
__global__ __launch_bounds__(256) void k_all(
    const float* __restrict__ z, const float* __restrict__ x,
    const float* __restrict__ Wb, const float* __restrict__ bb,
    const float* __restrict__ wv,
    const float* __restrict__ gamma, const float* __restrict__ beta,
    float* __restrict__ out, float* __restrict__ ws)
{
    const int blk = blockIdx.x;
    const int t   = threadIdx.x;

    if (blk >= CORR_BLOCKS) {
        // ---------------- conv path ----------------
        const int b    = blk - CORR_BLOCKS;     // 0..511
        const int n    = b >> 4;                // 32 batches
        const int og   = b & 15;                // 16 channel-groups of 16
        const int half = t >> 7;                // 0..1
        const int t2   = t & 127;               // pixel float4 index
        const int t3   = t2 - 119;

        float4 a{}, b4{}, c4{}, za{}, zb{}, zc{};
        const float4* xb = (const float4*)(x + (size_t)n * 3 * P_);
        if (t2 < 121) { a = xb[t2]; b4 = xb[121 + t2]; c4 = xb[242 + t2]; }
        const float4* zp4 = (const float4*)(z + (size_t)n * 3 * ZP_);
        if (t2 >= 119) { za = zp4[t3]; zb = zp4[9 + t3]; zc = zp4[18 + t3]; }

#pragma unroll
        for (int it = 0; it < 8; ++it) {
            const int o = og * 16 + it * 2 + half;
            const float w0 = Wb[o * 3 + 0];
            const float w1 = Wb[o * 3 + 1];
            const float w2 = Wb[o * 3 + 2];
            const float bi = bb[o];
            if (t2 < 121) {
                float4 r;
                r.x = fmaxf(0.f, fmaf(a.x, w0, fmaf(b4.x, w1, fmaf(c4.x, w2, bi))));
                r.y = fmaxf(0.f, fmaf(a.y, w0, fmaf(b4.y, w1, fmaf(c4.y, w2, bi))));
                r.z = fmaxf(0.f, fmaf(a.z, w0, fmaf(b4.z, w1, fmaf(c4.z, w2, bi))));
                r.w = fmaxf(0.f, fmaf(a.w, w0, fmaf(b4.w, w1, fmaf(c4.w, w2, bi))));
                ((float4*)(out + XF_OFF + (size_t)(n * C_ + o) * P_))[t2] = r;
            }
            if (t2 >= 119) {
                float4 r;
                r.x = fmaxf(0.f, fmaf(za.x, w0, fmaf(zb.x, w1, fmaf(zc.x, w2, bi))));
                r.y = fmaxf(0.f, fmaf(za.y, w0, fmaf(zb.y, w1, fmaf(zc.y, w2, bi))));
                r.z = fmaxf(0.f, fmaf(za.z, w0, fmaf(zb.z, w1, fmaf(zc.z, w2, bi))));
                r.w = fmaxf(0.f, fmaf(za.w, w0, fmaf(zb.w, w1, fmaf(zc.w, w2, bi))));
                ((float4*)(out + ZF_OFF + (size_t)(n * C_ + o) * ZP_))[t3] = r;
            }
        }
        return;
    }

    // ---------------- correlation path ----------------
    const int n = blk / HO_;
    const int i = blk % HO_;
    const int c = t;

    __shared__ float xs[3][6][22];   // x[n], 3 ch, rows i..i+5
    __shared__ float zs[3 * ZP_];    // z[n]
    __shared__ float red[4][HO_];
    __shared__ float sc[HO_];
    __shared__ int   isLast;
    __shared__ double bnS[4], bnQ[4];
    __shared__ float fp[2];

    const float* xp = x + (size_t)n * (3 * P_);
    for (int u = c; u < 3 * 6 * 22; u += 256) {
        const int ch = u / 132;
        const int rr = (u % 132) / 22;
        const int uu = u % 22;
        xs[ch][rr][uu] = xp[ch * P_ + (i + rr) * 22 + uu];
    }
    const float* zp = z + (size_t)n * (3 * ZP_);
    for (int u = c; u < 3 * ZP_; u += 256) zs[u] = zp[u];
    __syncthreads();

    const float w0 = Wb[c * 3 + 0];
    const float w1 = Wb[c * 3 + 1];
    const float w2 = Wb[c * 3 + 2];
    const float bi = bb[c];
    const float wc = wv[c] * (1.f / 36.f);

    float szv[ZP_];
#pragma unroll
    for (int k = 0; k < ZP_; ++k) {
        const float v = fmaxf(0.f,
            fmaf(zs[k], w0, fmaf(zs[ZP_ + k], w1, fmaf(zs[2 * ZP_ + k], w2, bi))));
        szv[k] = wc * fsqrt(v);
    }

    float acc[HO_];
#pragma unroll
    for (int j = 0; j < HO_; ++j) acc[j] = 0.f;

#pragma unroll
    for (int r = 0; r < 6; ++r) {
        float sq[22];
#pragma unroll
        for (int u = 0; u < 22; ++u) {
            const float v = fmaxf(0.f,
                fmaf(xs[0][r][u], w0, fmaf(xs[1][r][u], w1, fmaf(xs[2][r][u], w2, bi))));
            sq[u] = fsqrt(v);
        }
#pragma unroll
        for (int kw = 0; kw < K_; ++kw) {
            const float s = szv[r * 6 + kw];
#pragma unroll
            for (int j = 0; j < HO_; ++j)
                acc[j] = fmaf(s, sq[j + kw], acc[j]);
        }
    }

    // wave64 sum reduce via DPP (result lands in lane 63)
#pragma unroll
    for (int j = 0; j < HO_; ++j) {
        DPP_ADD(acc[j], 0x111);   // row_shr:1
        DPP_ADD(acc[j], 0x112);   // row_shr:2
        DPP_ADD(acc[j], 0x114);   // row_shr:4
        DPP_ADD(acc[j], 0x118);   // row_shr:8
        DPP_ADD(acc[j], 0x142);   // row_bcast:15
        DPP_ADD(acc[j], 0x143);   // row_bcast:31 -> lane63 has wave sum
    }
    const int wave = c >> 6;
    const int lane = c & 63;
    if (lane == 63) {
#pragma unroll
        for (int j = 0; j < HO_; ++j) red[wave][j] = acc[j];
    }
    __syncthreads();
    if (c < HO_) {
        const float v = red[0][c] + red[1][c] + red[2][c] + red[3][c];
        out[n * (HO_ * HO_) + i * HO_ + c] = v;   // pre-BN score
        sc[c] = v;
    }
    __syncthreads();   // drains the score stores (wave 0) before release

    unsigned* cnt = (unsigned*)((char*)ws + CNT_OFF_BYTES);
    if (c == 0) {
        float s = 0.f, q = 0.f;
#pragma unroll
        for (int j = 0; j < HO_; ++j) { s += sc[j]; q += sc[j] * sc[j]; }
        ws[blk * 2 + 0] = s;
        ws[blk * 2 + 1] = q;
        __threadfence();                       // release: partials + scores -> coherent point
        const unsigned old = atomicAdd(cnt, 1u);
        isLast = (old == (unsigned)(CORR_BLOCKS - 1)) ? 1 : 0;
    }
    __syncthreads();

    if (isLast) {
        if (c == 0) __threadfence();           // acquire: invalidate caches
        __syncthreads();

        // reduce 544 (sum,sumsq) partials in double
        double s = 0.0, q = 0.0;
        for (int u = c; u < CORR_BLOCKS; u += 256) {
            s += (double)ws[2 * u];
            q += (double)ws[2 * u + 1];
        }
#pragma unroll
        for (int off = 1; off < 64; off <<= 1) {
            s += __shfl_xor(s, off, 64);
            q += __shfl_xor(q, off, 64);
        }
        if (lane == 0) { bnS[wave] = s; bnQ[wave] = q; }
        __syncthreads();
        if (c == 0) {
            double S = 0.0, Q = 0.0;
#pragma unroll
            for (int w = 0; w < 4; ++w) { S += bnS[w]; Q += bnQ[w]; }
            const double mu  = S / (double)OUT0_SZ;
            const double var = Q / (double)OUT0_SZ - mu * mu;
            fp[0] = (float)mu;
            fp[1] = (float)((double)gamma[0] / sqrt(var + 1e-5));
        }
        __syncthreads();
        const float mu = fp[0], scale = fp[1], sh = beta[0];
        for (int idx = c; idx < OUT0_SZ; idx += 256)
            out[idx] = (out[idx] - mu) * scale + sh;
    }
}

// ---------------------------------------------------------------------------
extern "C" void kernel_launch(void* const* d_in, const int* in_sizes, int n_in,
                              void* d_out, int out_size, void* d_ws, size_t ws_size,
                              hipStream_t stream) {
    const float* z     = (const float*)d_in[0];
    const float* x     = (const float*)d_in[1];
    const float* Wb    = (const float*)d_in[2];
    const float* bb    = (const float*)d_in[3];
    const float* wv    = (const float*)d_in[4];
    const float* gamma = (const float*)d_in[5];
    const float* beta  = (const float*)d_in[6];
    float* out = (float*)d_out;
    float* ws  = (float*)d_ws;

    // zero the completion counter (deterministic per call; graph-capturable)
    hipMemsetAsync((char*)d_ws + CNT_OFF_BYTES, 0, 4, stream);
    k_all<<<CORR_BLOCKS + CONV_BLOCKS, 256, 0, stream>>>(
        z, x, Wb, bb, wv, gamma, beta, out, ws);
}